// Round 2
// baseline (6195.779 us; speedup 1.0000x reference)
//
#include <hip/hip_runtime.h>

static constexpr int SEQ   = 256;
static constexpr int BATCH = 32;
static constexpr int EMB   = 25;
static constexpr int HID   = 4096;
static constexpr int NBLK  = 256;           // one block per CU (co-resident)
static constexpr int NTHR  = 256;           // 4 waves, 1 per SIMD
static constexpr int RPB   = HID / NBLK;    // 16 rows of W_hh per block
static constexpr int CPT   = HID / NTHR;    // 16 cols per thread

// Persistent kernel, normal launch. W_hh register-resident (16x16 fp32/thread
// = 256 VGPRs). Hand-rolled monotonic grid barrier in d_ws with device-scope
// atomics (no cooperative launch, no cg). fp64 accumulation for the recurrent
// dot to stay numerically close to the numpy reference.
__global__ __launch_bounds__(NTHR, 1)
void rnn_persistent(const float* __restrict__ x,
                    const float* __restrict__ W_ih,
                    const float* __restrict__ W_hh,
                    const float* __restrict__ b_ih,
                    const float* __restrict__ b_hh,
                    float* __restrict__ out,
                    unsigned* __restrict__ bar,   // d_ws[0], zeroed by memset
                    float* __restrict__ hbuf)     // 2*HID floats, no init needed
{
    const int blk  = blockIdx.x;
    const int tid  = threadIdx.x;
    const int R0   = blk * RPB;
    const int C0   = tid * CPT;
    const int wave = tid >> 6;
    const int lane = tid & 63;

    __shared__ float ldsW[RPB * EMB];     // W_ih rows for this block
    __shared__ float ldsP[SEQ][RPB];      // 16 KB: precomputed input projection
    __shared__ float ldsRed[4][RPB];      // cross-wave partials

    // ---- W_ih slice -> LDS ----
    for (int i = tid; i < RPB * EMB; i += NTHR)
        ldsW[i] = W_ih[(size_t)R0 * EMB + i];
    __syncthreads();

    // ---- precompute p[step][row] = x[step][31]·W_ih[row] + b_ih + b_hh ----
    for (int idx = tid; idx < SEQ * RPB; idx += NTHR) {
        const int s = idx >> 4;          // RPB == 16
        const int r = idx & 15;
        const float* xt = x + ((size_t)s * BATCH + (BATCH - 1)) * EMB;
        float p = b_ih[R0 + r] + b_hh[R0 + r];
#pragma unroll
        for (int e = 0; e < EMB; ++e)
            p = fmaf(xt[e], ldsW[r * EMB + e], p);
        ldsP[s][r] = p;
    }

    // ---- register-resident W_hh tile (static indexing only -> VGPRs) ----
    float w[RPB][CPT];
#pragma unroll
    for (int r = 0; r < RPB; ++r) {
        const float4* src = reinterpret_cast<const float4*>(
            W_hh + (size_t)(R0 + r) * HID + C0);
#pragma unroll
        for (int q = 0; q < 4; ++q) {
            const float4 v = src[q];
            w[r][4*q+0] = v.x; w[r][4*q+1] = v.y;
            w[r][4*q+2] = v.z; w[r][4*q+3] = v.w;
        }
    }
    __syncthreads();   // ldsP complete before use

    for (int step = 0; step < SEQ; ++step) {
        // ---- h_t (step 0: zeros; else double-buffered global) ----
        float hv[CPT];
        if (step == 0) {
#pragma unroll
            for (int c = 0; c < CPT; ++c) hv[c] = 0.0f;
        } else {
            const float4* hs = reinterpret_cast<const float4*>(
                hbuf + ((step & 1) ^ 1) * HID + C0);
#pragma unroll
            for (int q = 0; q < 4; ++q) {
                const float4 v = hs[q];
                hv[4*q+0] = v.x; hv[4*q+1] = v.y;
                hv[4*q+2] = v.z; hv[4*q+3] = v.w;
            }
        }

        // ---- partial dots, fp64 accumulate (w fp32 in VGPRs) ----
        double acc[RPB];
#pragma unroll
        for (int r = 0; r < RPB; ++r) acc[r] = 0.0;
#pragma unroll
        for (int c = 0; c < CPT; ++c) {
            const double hd = (double)hv[c];
#pragma unroll
            for (int r = 0; r < RPB; ++r)
                acc[r] = fma((double)w[r][c], hd, acc[r]);
        }

        // ---- reduce: fp32 butterfly across wave, LDS across waves ----
        float accf[RPB];
#pragma unroll
        for (int r = 0; r < RPB; ++r) accf[r] = (float)acc[r];
#pragma unroll
        for (int off = 32; off >= 1; off >>= 1)
#pragma unroll
            for (int r = 0; r < RPB; ++r)
                accf[r] += __shfl_xor(accf[r], off, 64);
        if (lane == 0) {
#pragma unroll
            for (int r = 0; r < RPB; ++r)
                ldsRed[wave][r] = accf[r];
        }
        __syncthreads();

        if (tid < RPB) {
            const float s4 = ldsRed[0][tid] + ldsRed[1][tid]
                           + ldsRed[2][tid] + ldsRed[3][tid];
            const float h = tanhf(s4 + ldsP[step][tid]);
            out[(size_t)step * HID + R0 + tid] = h;
            hbuf[(step & 1) * HID + R0 + tid]  = h;
        }

        // ---- grid barrier: monotonic counter, device-scope ----
        __syncthreads();          // h writes + ldsRed reads done block-wide
        if (tid == 0) {
            __threadfence();      // release h stores device-wide
            __hip_atomic_fetch_add(bar, 1u, __ATOMIC_RELEASE,
                                   __HIP_MEMORY_SCOPE_AGENT);
            const unsigned target = (unsigned)NBLK * (unsigned)(step + 1);
            // bounded spin (~bailout only if residency assumption broke)
            for (long i = 0; i < (1L << 22); ++i) {
                if (__hip_atomic_load(bar, __ATOMIC_ACQUIRE,
                                      __HIP_MEMORY_SCOPE_AGENT) >= target)
                    break;
                __builtin_amdgcn_s_sleep(1);
            }
            __threadfence();      // acquire side before anyone reads h
        }
        __syncthreads();
    }
}

extern "C" void kernel_launch(void* const* d_in, const int* in_sizes, int n_in,
                              void* d_out, int out_size, void* d_ws, size_t ws_size,
                              hipStream_t stream) {
    const float* x    = (const float*)d_in[0];
    const float* W_ih = (const float*)d_in[1];
    const float* W_hh = (const float*)d_in[2];
    const float* b_ih = (const float*)d_in[3];
    const float* b_hh = (const float*)d_in[4];
    float* out = (float*)d_out;

    unsigned* bar = (unsigned*)d_ws;                    // [0..255]: barrier
    float* hbuf   = (float*)((char*)d_ws + 256);        // 2*HID floats

    // zero the barrier counter (d_ws is poisoned 0xAA before every call)
    hipMemsetAsync(d_ws, 0, 256, stream);

    rnn_persistent<<<dim3(NBLK), dim3(NTHR), 0, stream>>>(
        x, W_ih, W_hh, b_ih, b_hh, out, bar, hbuf);
}

// Round 4
// 5465.616 us; speedup vs baseline: 1.1336x; 1.1336x over previous
//
#include <hip/hip_runtime.h>

static constexpr int SEQ   = 256;
static constexpr int BATCH = 32;
static constexpr int EMB   = 25;
static constexpr int HID   = 4096;
static constexpr int NBLK  = 256;           // one block per CU (co-resident)
static constexpr int NTHR  = 256;           // 4 waves, 1 per SIMD
static constexpr int RPB   = HID / NBLK;    // 16 rows of W_hh per block
static constexpr int CPT   = HID / NTHR;    // 16 cols per thread

typedef unsigned u32x4 __attribute__((ext_vector_type(4)));

// Persistent kernel. W_hh register-resident (16x16 fp32/thread). Grid barrier
// via distributed per-block flags: arrival = plain device-scope store (no RMW
// serialization); detect = wave0 polls all 256 flags with cache-bypassing
// dwordx4 loads + __all ballot. fp64 accumulation for the recurrent dot.
__global__ __launch_bounds__(NTHR, 1)
void rnn_persistent(const float* __restrict__ x,
                    const float* __restrict__ W_ih,
                    const float* __restrict__ W_hh,
                    const float* __restrict__ b_ih,
                    const float* __restrict__ b_hh,
                    float* __restrict__ out,
                    unsigned* __restrict__ flags,  // 256 u32, zeroed by memset
                    float* __restrict__ hbuf)      // 2*HID floats, no init
{
    const int blk  = blockIdx.x;
    const int tid  = threadIdx.x;
    const int R0   = blk * RPB;
    const int C0   = tid * CPT;
    const int wave = tid >> 6;
    const int lane = tid & 63;

    __shared__ float ldsW[RPB * EMB];     // W_ih rows for this block
    __shared__ float ldsP[SEQ][RPB];      // precomputed input projection
    __shared__ float ldsRed[4][RPB];      // cross-wave partials

    // ---- W_ih slice -> LDS ----
    for (int i = tid; i < RPB * EMB; i += NTHR)
        ldsW[i] = W_ih[(size_t)R0 * EMB + i];
    __syncthreads();

    // ---- precompute p[step][row] = x[step][31]·W_ih[row] + b_ih + b_hh ----
    for (int idx = tid; idx < SEQ * RPB; idx += NTHR) {
        const int s = idx >> 4;
        const int r = idx & 15;
        const float* xt = x + ((size_t)s * BATCH + (BATCH - 1)) * EMB;
        float p = b_ih[R0 + r] + b_hh[R0 + r];
#pragma unroll
        for (int e = 0; e < EMB; ++e)
            p = fmaf(xt[e], ldsW[r * EMB + e], p);
        ldsP[s][r] = p;
    }

    // ---- register-resident W_hh tile (static indexing only -> regs) ----
    float w[RPB][CPT];
#pragma unroll
    for (int r = 0; r < RPB; ++r) {
        const float4* src = reinterpret_cast<const float4*>(
            W_hh + (size_t)(R0 + r) * HID + C0);
#pragma unroll
        for (int q = 0; q < 4; ++q) {
            const float4 v = src[q];
            w[r][4*q+0] = v.x; w[r][4*q+1] = v.y;
            w[r][4*q+2] = v.z; w[r][4*q+3] = v.w;
        }
    }
    __syncthreads();   // ldsP complete before use

    for (int step = 0; step < SEQ; ++step) {
        // ---- h_t (step 0: zeros; else double-buffered global) ----
        float hv[CPT];
        if (step == 0) {
#pragma unroll
            for (int c = 0; c < CPT; ++c) hv[c] = 0.0f;
        } else {
            const float4* hs = reinterpret_cast<const float4*>(
                hbuf + ((step & 1) ^ 1) * HID + C0);
#pragma unroll
            for (int q = 0; q < 4; ++q) {
                const float4 v = hs[q];
                hv[4*q+0] = v.x; hv[4*q+1] = v.y;
                hv[4*q+2] = v.z; hv[4*q+3] = v.w;
            }
        }

        // ---- partial dots, fp64 accumulate (w fp32 in regs) ----
        double acc[RPB];
#pragma unroll
        for (int r = 0; r < RPB; ++r) acc[r] = 0.0;
#pragma unroll
        for (int c = 0; c < CPT; ++c) {
            const double hd = (double)hv[c];
#pragma unroll
            for (int r = 0; r < RPB; ++r)
                acc[r] = fma((double)w[r][c], hd, acc[r]);
        }

        // ---- reduce: fp32 butterfly across wave, LDS across waves ----
        float accf[RPB];
#pragma unroll
        for (int r = 0; r < RPB; ++r) accf[r] = (float)acc[r];
#pragma unroll
        for (int off = 32; off >= 1; off >>= 1)
#pragma unroll
            for (int r = 0; r < RPB; ++r)
                accf[r] += __shfl_xor(accf[r], off, 64);
        if (lane == 0) {
#pragma unroll
            for (int r = 0; r < RPB; ++r)
                ldsRed[wave][r] = accf[r];
        }
        __syncthreads();

        if (tid < RPB) {
            const float s4 = ldsRed[0][tid] + ldsRed[1][tid]
                           + ldsRed[2][tid] + ldsRed[3][tid];
            const float h = tanhf(s4 + ldsP[step][tid]);
            out[(size_t)step * HID + R0 + tid] = h;
            // agent-scope relaxed store: write-through past L2 so remote
            // XCDs see it without relying on a full L2 writeback
            __hip_atomic_store(&hbuf[(step & 1) * HID + R0 + tid], h,
                               __ATOMIC_RELAXED, __HIP_MEMORY_SCOPE_AGENT);
        }

        if (step == SEQ - 1) break;   // nobody consumes h after last step

        // ---- grid barrier: flag store + poll-all (no atomic RMW) ----
        __syncthreads();              // h writes done block-wide
        if (wave == 0) {
            const unsigned target = (unsigned)(step + 1);
            if (lane == 0) {
                __threadfence();      // order h stores before flag store
                __hip_atomic_store(&flags[blk], target,
                                   __ATOMIC_RELEASE, __HIP_MEMORY_SCOPE_AGENT);
            }
            const unsigned* fp = flags + lane * 4;   // 64 lanes x 4 = 256
            for (int it = 0; it < (1 << 18); ++it) {
                u32x4 v;
                asm volatile(
                    "global_load_dwordx4 %0, %1, off sc0 sc1\n\t"
                    "s_waitcnt vmcnt(0)"
                    : "=v"(v) : "v"(fp) : "memory");
                const bool ok = (v[0] >= target) & (v[1] >= target) &
                                (v[2] >= target) & (v[3] >= target);
                if (__all(ok)) break;
                __builtin_amdgcn_s_sleep(2);
            }
            if (lane == 0) {
                // acquire: invalidate stale L1/L2 before hbuf reads
                (void)__hip_atomic_load(&flags[0], __ATOMIC_ACQUIRE,
                                        __HIP_MEMORY_SCOPE_AGENT);
                __threadfence();
            }
        }
        __syncthreads();
    }
}

extern "C" void kernel_launch(void* const* d_in, const int* in_sizes, int n_in,
                              void* d_out, int out_size, void* d_ws, size_t ws_size,
                              hipStream_t stream) {
    const float* x    = (const float*)d_in[0];
    const float* W_ih = (const float*)d_in[1];
    const float* W_hh = (const float*)d_in[2];
    const float* b_ih = (const float*)d_in[3];
    const float* b_hh = (const float*)d_in[4];
    float* out = (float*)d_out;

    unsigned* flags = (unsigned*)d_ws;                  // 256 u32 = 1 KB
    float* hbuf     = (float*)((char*)d_ws + 4096);     // 2*HID floats

    // zero the flags (d_ws is re-poisoned 0xAA before every timed call)
    hipMemsetAsync(d_ws, 0, 4096, stream);

    rnn_persistent<<<dim3(NBLK), dim3(NTHR), 0, stream>>>(
        x, W_ih, W_hh, b_ih, b_hh, out, flags, hbuf);
}

// Round 8
// 2082.680 us; speedup vs baseline: 2.9749x; 2.6243x over previous
//
#include <hip/hip_runtime.h>

static constexpr int SEQ   = 256;
static constexpr int BATCH = 32;
static constexpr int EMB   = 25;
static constexpr int HID   = 4096;
static constexpr int NBLK  = 256;           // one block per CU (co-resident)
static constexpr int NTHR  = 256;           // 4 waves, 1 per SIMD
static constexpr int RPB   = HID / NBLK;    // 16 rows of W_hh per block
static constexpr int CPT   = HID / NTHR;    // 16 cols per thread

typedef unsigned u32x4 __attribute__((ext_vector_type(4)));
typedef float    f32x4 __attribute__((ext_vector_type(4)));

// Persistent kernel, fence-free grid barrier. All cross-block data (h, flags)
// moves via sc0 sc1 (L1/L2-bypass, memory-side L3 = coherence point) inline-asm
// loads/stores. Release = s_waitcnt vmcnt(0) then flag store. Poll predicate is
// poison-proof: legit flags are 1..255, so (v >= target && v < 0x10000) never
// passes on leftover 0xAAAAAAAA poison — no reliance on memset visibility.
__global__ __launch_bounds__(NTHR, 1)
void rnn_persistent(const float* __restrict__ x,
                    const float* __restrict__ W_ih,
                    const float* __restrict__ W_hh,
                    const float* __restrict__ b_ih,
                    const float* __restrict__ b_hh,
                    float* __restrict__ out,
                    unsigned* __restrict__ flags,  // 256 u32 (memset 0; poll is
                    float* __restrict__ hbuf)      //  poison-proof regardless)
{
    const int blk  = blockIdx.x;
    const int tid  = threadIdx.x;
    const int R0   = blk * RPB;
    const int C0   = tid * CPT;
    const int wave = tid >> 6;
    const int lane = tid & 63;

    __shared__ float ldsW[RPB * EMB];     // W_ih rows for this block
    __shared__ float ldsP[SEQ][RPB];      // precomputed input projection
    __shared__ float ldsRed[4][RPB];      // cross-wave partials

    // ---- W_ih slice -> LDS ----
    for (int i = tid; i < RPB * EMB; i += NTHR)
        ldsW[i] = W_ih[(size_t)R0 * EMB + i];
    __syncthreads();

    // ---- precompute p[step][row] = x[step][31]·W_ih[row] + b_ih + b_hh ----
    for (int idx = tid; idx < SEQ * RPB; idx += NTHR) {
        const int s = idx >> 4;
        const int r = idx & 15;
        const float* xt = x + ((size_t)s * BATCH + (BATCH - 1)) * EMB;
        float p = b_ih[R0 + r] + b_hh[R0 + r];
#pragma unroll
        for (int e = 0; e < EMB; ++e)
            p = fmaf(xt[e], ldsW[r * EMB + e], p);
        ldsP[s][r] = p;
    }

    // ---- register-resident W_hh tile (static indexing only -> regs) ----
    float w[RPB][CPT];
#pragma unroll
    for (int r = 0; r < RPB; ++r) {
        const float4* src = reinterpret_cast<const float4*>(
            W_hh + (size_t)(R0 + r) * HID + C0);
#pragma unroll
        for (int q = 0; q < 4; ++q) {
            const float4 v = src[q];
            w[r][4*q+0] = v.x; w[r][4*q+1] = v.y;
            w[r][4*q+2] = v.z; w[r][4*q+3] = v.w;
        }
    }
    __syncthreads();   // ldsP complete before use

    for (int step = 0; step < SEQ; ++step) {
        // ---- h_t: sc0 sc1 bypass loads from L3 (never stale) ----
        float hv[CPT];
        if (step == 0) {
#pragma unroll
            for (int c = 0; c < CPT; ++c) hv[c] = 0.0f;
        } else {
            const float* hp = hbuf + ((step & 1) ^ 1) * HID + C0;
            f32x4 a0, a1, a2, a3;
            asm volatile(
                "global_load_dwordx4 %0, %4, off sc0 sc1\n\t"
                "global_load_dwordx4 %1, %4, off offset:16 sc0 sc1\n\t"
                "global_load_dwordx4 %2, %4, off offset:32 sc0 sc1\n\t"
                "global_load_dwordx4 %3, %4, off offset:48 sc0 sc1\n\t"
                "s_waitcnt vmcnt(0)"
                : "=&v"(a0), "=&v"(a1), "=&v"(a2), "=&v"(a3)
                : "v"(hp) : "memory");
#pragma unroll
            for (int q = 0; q < 4; ++q) {
                hv[0*4+q] = a0[q]; hv[1*4+q] = a1[q];
                hv[2*4+q] = a2[q]; hv[3*4+q] = a3[q];
            }
        }

        // ---- partial dots, fp64 accumulate (w fp32 in regs) ----
        double acc[RPB];
#pragma unroll
        for (int r = 0; r < RPB; ++r) acc[r] = 0.0;
#pragma unroll
        for (int c = 0; c < CPT; ++c) {
            const double hd = (double)hv[c];
#pragma unroll
            for (int r = 0; r < RPB; ++r)
                acc[r] = fma((double)w[r][c], hd, acc[r]);
        }

        // ---- reduce: fp32 butterfly across wave, LDS across waves ----
        float accf[RPB];
#pragma unroll
        for (int r = 0; r < RPB; ++r) accf[r] = (float)acc[r];
#pragma unroll
        for (int off = 32; off >= 1; off >>= 1)
#pragma unroll
            for (int r = 0; r < RPB; ++r)
                accf[r] += __shfl_xor(accf[r], off, 64);
        if (lane == 0) {
#pragma unroll
            for (int r = 0; r < RPB; ++r)
                ldsRed[wave][r] = accf[r];
        }
        __syncthreads();

        // ---- epilogue + fence-free release + poll, all in wave 0 ----
        if (wave == 0) {
            float h = 0.0f;
            if (lane < RPB) {
                const float s4 = ldsRed[0][lane] + ldsRed[1][lane]
                               + ldsRed[2][lane] + ldsRed[3][lane];
                h = tanhf(s4 + ldsP[step][lane]);
                float* hd = hbuf + (step & 1) * HID + R0 + lane;
                asm volatile("global_store_dword %0, %1, off sc0 sc1"
                             :: "v"(hd), "v"(h) : "memory");
            }
            if (step < SEQ - 1) {
                // release: h stores (all in this wave) ack'd at L3 first
                asm volatile("s_waitcnt vmcnt(0)" ::: "memory");
                if (lane == 0) {
                    const unsigned tv = (unsigned)(step + 1);
                    unsigned* fa = flags + blk;
                    asm volatile("global_store_dword %0, %1, off sc0 sc1"
                                 :: "v"(fa), "v"(tv) : "memory");
                }
            }
            if (lane < RPB)   // off the critical path
                out[(size_t)step * HID + R0 + lane] = h;
            if (step < SEQ - 1) {
                const unsigned target = (unsigned)(step + 1);
                const unsigned* fp = flags + lane * 4;   // 64 x 4 = 256
                for (int it = 0; it < (1 << 15); ++it) {
                    u32x4 v;
                    asm volatile(
                        "global_load_dwordx4 %0, %1, off sc0 sc1\n\t"
                        "s_waitcnt vmcnt(0)"
                        : "=v"(v) : "v"(fp) : "memory");
                    // poison-proof: legit values are 1..255; 0xAAAAAAAA or any
                    // garbage >= 0x10000 must NOT satisfy the barrier
                    const bool ok =
                        (v[0] >= target) & (v[0] < 0x10000u) &
                        (v[1] >= target) & (v[1] < 0x10000u) &
                        (v[2] >= target) & (v[2] < 0x10000u) &
                        (v[3] >= target) & (v[3] < 0x10000u);
                    if (__all(ok)) break;
                    __builtin_amdgcn_s_sleep(1);
                }
            }
        }
        __syncthreads();   // waves 1-3 held here until wave 0 clears the poll
    }
}

extern "C" void kernel_launch(void* const* d_in, const int* in_sizes, int n_in,
                              void* d_out, int out_size, void* d_ws, size_t ws_size,
                              hipStream_t stream) {
    const float* x    = (const float*)d_in[0];
    const float* W_ih = (const float*)d_in[1];
    const float* W_hh = (const float*)d_in[2];
    const float* b_ih = (const float*)d_in[3];
    const float* b_hh = (const float*)d_in[4];
    float* out = (float*)d_out;

    unsigned* flags = (unsigned*)d_ws;                  // 256 u32 = 1 KB
    float* hbuf     = (float*)((char*)d_ws + 4096);     // 2*HID floats

    // zero the flags (poll is poison-proof even if this is slow to propagate)
    hipMemsetAsync(d_ws, 0, 4096, stream);

    rnn_persistent<<<dim3(NBLK), dim3(NTHR), 0, stream>>>(
        x, W_ih, W_hh, b_ih, b_hh, out, flags, hbuf);
}